// Round 1
// baseline (645.499 us; speedup 1.0000x reference)
//
#include <hip/hip_runtime.h>

#define N_NODES 100000
#define N_EDGES 1600000
#define DIN 256
#define DHID 128
#define DOUT 64

// ---------------- degree / norm ----------------

__global__ void k_count(const int* __restrict__ col, int* __restrict__ cnt) {
  int i = blockIdx.x * 256 + threadIdx.x;
  if (i < N_EDGES) atomicAdd(&cnt[col[i]], 1);
}

__global__ void k_dis(const int* __restrict__ cnt, float* __restrict__ dis) {
  int i = blockIdx.x * 256 + threadIdx.x;
  if (i < N_NODES) dis[i] = rsqrtf((float)cnt[i] + 1.0f);  // +1 self-loop
}

// ---------------- exclusive scan (3 kernels) ----------------

__global__ void k_scan1(const int* __restrict__ cnt, int* __restrict__ off,
                        int* __restrict__ bsum) {
  __shared__ int s[256];
  int t = threadIdx.x;
  int base = blockIdx.x * 1024 + t * 4;
  int v0 = (base + 0 < N_NODES) ? cnt[base + 0] : 0;
  int v1 = (base + 1 < N_NODES) ? cnt[base + 1] : 0;
  int v2 = (base + 2 < N_NODES) ? cnt[base + 2] : 0;
  int v3 = (base + 3 < N_NODES) ? cnt[base + 3] : 0;
  int mysum = v0 + v1 + v2 + v3;
  s[t] = mysum;
  __syncthreads();
  for (int d = 1; d < 256; d <<= 1) {
    int y = (t >= d) ? s[t - d] : 0;
    __syncthreads();
    s[t] += y;
    __syncthreads();
  }
  int run = s[t] - mysum;  // exclusive prefix of this thread's 4 elements
  if (base + 0 < N_NODES) off[base + 0] = run; run += v0;
  if (base + 1 < N_NODES) off[base + 1] = run; run += v1;
  if (base + 2 < N_NODES) off[base + 2] = run; run += v2;
  if (base + 3 < N_NODES) off[base + 3] = run;
  if (t == 255) bsum[blockIdx.x] = s[255];
}

__global__ void k_scan2(int* __restrict__ bsum, int* __restrict__ off) {
  __shared__ int s[256];
  int t = threadIdx.x;
  const int nb = (N_NODES + 1023) / 1024;  // 98
  int v = (t < nb) ? bsum[t] : 0;
  s[t] = v;
  __syncthreads();
  for (int d = 1; d < 256; d <<= 1) {
    int y = (t >= d) ? s[t - d] : 0;
    __syncthreads();
    s[t] += y;
    __syncthreads();
  }
  if (t < nb) bsum[t] = s[t] - v;
  if (t == 255) off[N_NODES] = s[255];  // == N_EDGES
}

__global__ void k_scan3(int* __restrict__ off, const int* __restrict__ bsum) {
  int i = blockIdx.x * 256 + threadIdx.x;
  if (i < N_NODES) off[i] += bsum[i >> 10];
}

// ---------------- CSR scatter (counting sort by dst) ----------------

__global__ void k_scatter(const int* __restrict__ rowp, const int* __restrict__ colp,
                          const float* __restrict__ dis, const int* __restrict__ off,
                          int* __restrict__ cursor, int* __restrict__ ssrc,
                          float* __restrict__ sw) {
  int e = blockIdx.x * 256 + threadIdx.x;
  if (e < N_EDGES) {
    int c = colp[e], r = rowp[e];
    int p = off[c] + atomicAdd(&cursor[c], 1);
    ssrc[p] = r;
    sw[p] = dis[r] * dis[c];
  }
}

// ---------------- GEMM1: h1[N,128] = x[N,256] @ W1[256,128] ----------------
// block = 256 threads, 64 rows/block; thread: 8 rows x 4 cols register tile.

__global__ __launch_bounds__(256) void k_gemm1(const float* __restrict__ x,
                                               const float* __restrict__ W,
                                               float* __restrict__ h) {
  __shared__ float xs[64 * 256];  // 64 KB
  float4* xs4 = (float4*)xs;
  int row0 = blockIdx.x * 64;
  const float4* xg = (const float4*)x;
  for (int idx = threadIdx.x; idx < 64 * 64; idx += 256) {
    int r = idx >> 6, kk = idx & 63;
    float4 v = make_float4(0.f, 0.f, 0.f, 0.f);
    int gr = row0 + r;
    if (gr < N_NODES) v = xg[(size_t)gr * 64 + kk];
    xs4[idx] = v;
  }
  __syncthreads();
  int c  = threadIdx.x & 31;
  int rg = threadIdx.x >> 5;  // 0..7
  float acc[8][4];
#pragma unroll
  for (int j = 0; j < 8; j++)
#pragma unroll
    for (int cc = 0; cc < 4; cc++) acc[j][cc] = 0.f;

  for (int k4 = 0; k4 < 64; k4++) {
    float w[4][4];
#pragma unroll
    for (int kk = 0; kk < 4; kk++)
#pragma unroll
      for (int cc = 0; cc < 4; cc++)
        w[kk][cc] = W[(k4 * 4 + kk) * DHID + cc * 32 + c];
#pragma unroll
    for (int j = 0; j < 8; j++) {
      float4 xv = xs4[(rg * 8 + j) * 64 + k4];
#pragma unroll
      for (int cc = 0; cc < 4; cc++) {
        acc[j][cc] = fmaf(xv.x, w[0][cc], acc[j][cc]);
        acc[j][cc] = fmaf(xv.y, w[1][cc], acc[j][cc]);
        acc[j][cc] = fmaf(xv.z, w[2][cc], acc[j][cc]);
        acc[j][cc] = fmaf(xv.w, w[3][cc], acc[j][cc]);
      }
    }
  }
#pragma unroll
  for (int j = 0; j < 8; j++) {
    int r = row0 + rg * 8 + j;
    if (r < N_NODES) {
#pragma unroll
      for (int cc = 0; cc < 4; cc++)
        h[(size_t)r * DHID + cc * 32 + c] = acc[j][cc];
    }
  }
}

// ---------------- GEMM2: h2[N,64] = a1[N,128] @ W2[128,64] ----------------

__global__ __launch_bounds__(256) void k_gemm2(const float* __restrict__ a,
                                               const float* __restrict__ W,
                                               float* __restrict__ h) {
  __shared__ float xs[64 * 128];  // 32 KB
  float4* xs4 = (float4*)xs;
  int row0 = blockIdx.x * 64;
  const float4* ag = (const float4*)a;
  for (int idx = threadIdx.x; idx < 64 * 32; idx += 256) {
    int r = idx >> 5, kk = idx & 31;
    float4 v = make_float4(0.f, 0.f, 0.f, 0.f);
    int gr = row0 + r;
    if (gr < N_NODES) v = ag[(size_t)gr * 32 + kk];
    xs4[idx] = v;
  }
  __syncthreads();
  int c  = threadIdx.x & 31;
  int rg = threadIdx.x >> 5;  // 0..7
  float acc[8][2];
#pragma unroll
  for (int j = 0; j < 8; j++) {
    acc[j][0] = 0.f;
    acc[j][1] = 0.f;
  }
  for (int k4 = 0; k4 < 32; k4++) {
    float w[4][2];
#pragma unroll
    for (int kk = 0; kk < 4; kk++)
#pragma unroll
      for (int cc = 0; cc < 2; cc++)
        w[kk][cc] = W[(k4 * 4 + kk) * DOUT + cc * 32 + c];
#pragma unroll
    for (int j = 0; j < 8; j++) {
      float4 xv = xs4[(rg * 8 + j) * 32 + k4];
#pragma unroll
      for (int cc = 0; cc < 2; cc++) {
        acc[j][cc] = fmaf(xv.x, w[0][cc], acc[j][cc]);
        acc[j][cc] = fmaf(xv.y, w[1][cc], acc[j][cc]);
        acc[j][cc] = fmaf(xv.z, w[2][cc], acc[j][cc]);
        acc[j][cc] = fmaf(xv.w, w[3][cc], acc[j][cc]);
      }
    }
  }
#pragma unroll
  for (int j = 0; j < 8; j++) {
    int r = row0 + rg * 8 + j;
    if (r < N_NODES) {
      h[(size_t)r * DOUT + 0 * 32 + c]  = acc[j][0];
      h[(size_t)r * DOUT + 1 * 32 + c]  = acc[j][1];
    }
  }
}

// ---------------- aggregation layer 1 (wave per node, dim 128) ----------------

__global__ __launch_bounds__(256) void k_agg1(const float* __restrict__ h,
                                              const int* __restrict__ off,
                                              const int* __restrict__ src,
                                              const float* __restrict__ w,
                                              const float* __restrict__ dis,
                                              const float* __restrict__ b1,
                                              float* __restrict__ out) {
  int wid  = (blockIdx.x * 256 + threadIdx.x) >> 6;
  int lane = threadIdx.x & 63;
  if (wid >= N_NODES) return;
  float d = dis[wid];
  const float2* hp = (const float2*)h;
  float2 hv = hp[(size_t)wid * 64 + lane];
  float sl = d * d;  // self-loop norm
  float ax = hv.x * sl, ay = hv.y * sl;
  int o0 = off[wid], o1 = off[wid + 1];
  for (int e = o0; e < o1; e++) {
    int s  = src[e];
    float ww = w[e];
    float2 v = hp[(size_t)s * 64 + lane];
    ax = fmaf(v.x, ww, ax);
    ay = fmaf(v.y, ww, ay);
  }
  float2 bb = ((const float2*)b1)[lane];
  float2 r;
  r.x = fmaxf(ax + bb.x, 0.f);
  r.y = fmaxf(ay + bb.y, 0.f);
  ((float2*)out)[(size_t)wid * 64 + lane] = r;
}

// -------- aggregation layer 2 + bias + log_softmax (wave per node, dim 64) -----

__global__ __launch_bounds__(256) void k_agg2(const float* __restrict__ h,
                                              const int* __restrict__ off,
                                              const int* __restrict__ src,
                                              const float* __restrict__ w,
                                              const float* __restrict__ dis,
                                              const float* __restrict__ b2,
                                              float* __restrict__ out) {
  int wid  = (blockIdx.x * 256 + threadIdx.x) >> 6;
  int lane = threadIdx.x & 63;
  if (wid >= N_NODES) return;
  float d = dis[wid];
  float acc = h[(size_t)wid * 64 + lane] * d * d;
  int o0 = off[wid], o1 = off[wid + 1];
  for (int e = o0; e < o1; e++) {
    acc = fmaf(h[(size_t)src[e] * 64 + lane], w[e], acc);
  }
  float v = acc + b2[lane];
  float m = v;
#pragma unroll
  for (int sft = 32; sft >= 1; sft >>= 1) {
    float o = __shfl_xor(m, sft, 64);
    m = fmaxf(m, o);
  }
  float ex = expf(v - m);
  float sum = ex;
#pragma unroll
  for (int sft = 32; sft >= 1; sft >>= 1) sum += __shfl_xor(sum, sft, 64);
  out[(size_t)wid * 64 + lane] = v - m - logf(sum);
}

// ---------------- launch ----------------

extern "C" void kernel_launch(void* const* d_in, const int* in_sizes, int n_in,
                              void* d_out, int out_size, void* d_ws, size_t ws_size,
                              hipStream_t stream) {
  const float* x  = (const float*)d_in[0];
  const int*   ei = (const int*)d_in[1];
  const float* W1 = (const float*)d_in[2];
  const float* b1 = (const float*)d_in[3];
  const float* W2 = (const float*)d_in[4];
  const float* b2 = (const float*)d_in[5];
  float* out = (float*)d_out;
  const int* rowp = ei;            // sources
  const int* colp = ei + N_EDGES;  // destinations

  char* p = (char*)d_ws;
  size_t o = 0;
  auto alloc = [&](size_t bytes) -> void* {
    void* r = p + o;
    o = (o + bytes + 255) & ~(size_t)255;
    return r;
  };
  int*   cnt    = (int*)alloc((size_t)N_NODES * 4);
  int*   cursor = (int*)alloc((size_t)N_NODES * 4);
  int*   off    = (int*)alloc((size_t)(N_NODES + 1) * 4);
  int*   bsum   = (int*)alloc(256 * 4);
  float* dis    = (float*)alloc((size_t)N_NODES * 4);
  int*   ssrc   = (int*)alloc((size_t)N_EDGES * 4);
  float* swt    = (float*)alloc((size_t)N_EDGES * 4);
  float* h1     = (float*)alloc((size_t)N_NODES * DHID * 4);
  float* a1     = (float*)alloc((size_t)N_NODES * DHID * 4);
  float* h2     = h1;  // h1 dead after k_agg1; reuse for h2 (N x 64)

  hipMemsetAsync(cnt, 0, (size_t)N_NODES * 4, stream);
  hipMemsetAsync(cursor, 0, (size_t)N_NODES * 4, stream);

  k_count<<<(N_EDGES + 255) / 256, 256, 0, stream>>>(colp, cnt);
  k_dis<<<(N_NODES + 255) / 256, 256, 0, stream>>>(cnt, dis);
  k_scan1<<<(N_NODES + 1023) / 1024, 256, 0, stream>>>(cnt, off, bsum);
  k_scan2<<<1, 256, 0, stream>>>(bsum, off);
  k_scan3<<<(N_NODES + 255) / 256, 256, 0, stream>>>(off, bsum);
  k_scatter<<<(N_EDGES + 255) / 256, 256, 0, stream>>>(rowp, colp, dis, off, cursor, ssrc, swt);
  k_gemm1<<<(N_NODES + 63) / 64, 256, 0, stream>>>(x, W1, h1);
  k_agg1<<<(N_NODES + 3) / 4, 256, 0, stream>>>(h1, off, ssrc, swt, dis, b1, a1);
  k_gemm2<<<(N_NODES + 63) / 64, 256, 0, stream>>>(a1, W2, h2);
  k_agg2<<<(N_NODES + 3) / 4, 256, 0, stream>>>(h2, off, ssrc, swt, dis, b2, out);
}

// Round 2
// 357.010 us; speedup vs baseline: 1.8081x; 1.8081x over previous
//
#include <hip/hip_runtime.h>

#define N_NODES 100000
#define N_EDGES 1600000
#define DIN 256
#define DHID 128
#define DOUT 64

typedef __attribute__((ext_vector_type(8))) short bf16x8;
typedef __attribute__((ext_vector_type(4))) float f32x4;

static __device__ __forceinline__ ushort f2bf(float f) {
  union { float f; uint u; } a; a.f = f;
  uint u = a.u;
  uint r = u + 0x7fffu + ((u >> 16) & 1u);  // RNE
  return (ushort)(r >> 16);
}
static __device__ __forceinline__ float bf2f(ushort h) {
  return __uint_as_float(((uint)h) << 16);
}

// ---------------- degree / norm ----------------

__global__ void k_count(const int* __restrict__ col, int* __restrict__ cnt) {
  int i = blockIdx.x * 256 + threadIdx.x;
  if (i < N_EDGES) atomicAdd(&cnt[col[i]], 1);
}

__global__ void k_dis(const int* __restrict__ cnt, float* __restrict__ dis) {
  int i = blockIdx.x * 256 + threadIdx.x;
  if (i < N_NODES) dis[i] = rsqrtf((float)cnt[i] + 1.0f);  // +1 self-loop
}

// ---------------- exclusive scan (3 kernels) ----------------

__global__ void k_scan1(const int* __restrict__ cnt, int* __restrict__ off,
                        int* __restrict__ bsum) {
  __shared__ int s[256];
  int t = threadIdx.x;
  int base = blockIdx.x * 1024 + t * 4;
  int v0 = (base + 0 < N_NODES) ? cnt[base + 0] : 0;
  int v1 = (base + 1 < N_NODES) ? cnt[base + 1] : 0;
  int v2 = (base + 2 < N_NODES) ? cnt[base + 2] : 0;
  int v3 = (base + 3 < N_NODES) ? cnt[base + 3] : 0;
  int mysum = v0 + v1 + v2 + v3;
  s[t] = mysum;
  __syncthreads();
  for (int d = 1; d < 256; d <<= 1) {
    int y = (t >= d) ? s[t - d] : 0;
    __syncthreads();
    s[t] += y;
    __syncthreads();
  }
  int run = s[t] - mysum;
  if (base + 0 < N_NODES) off[base + 0] = run; run += v0;
  if (base + 1 < N_NODES) off[base + 1] = run; run += v1;
  if (base + 2 < N_NODES) off[base + 2] = run; run += v2;
  if (base + 3 < N_NODES) off[base + 3] = run;
  if (t == 255) bsum[blockIdx.x] = s[255];
}

__global__ void k_scan2(int* __restrict__ bsum, int* __restrict__ off) {
  __shared__ int s[256];
  int t = threadIdx.x;
  const int nb = (N_NODES + 1023) / 1024;
  int v = (t < nb) ? bsum[t] : 0;
  s[t] = v;
  __syncthreads();
  for (int d = 1; d < 256; d <<= 1) {
    int y = (t >= d) ? s[t - d] : 0;
    __syncthreads();
    s[t] += y;
    __syncthreads();
  }
  if (t < nb) bsum[t] = s[t] - v;
  if (t == 255) off[N_NODES] = s[255];
}

__global__ void k_scan3(int* __restrict__ off, const int* __restrict__ bsum) {
  int i = blockIdx.x * 256 + threadIdx.x;
  if (i < N_NODES) off[i] += bsum[i >> 10];
}

// ---------------- CSR scatter ----------------

__global__ void k_scatter(const int* __restrict__ rowp, const int* __restrict__ colp,
                          const float* __restrict__ dis, const int* __restrict__ off,
                          int* __restrict__ cursor, int* __restrict__ ssrc,
                          float* __restrict__ sw) {
  int e = blockIdx.x * 256 + threadIdx.x;
  if (e < N_EDGES) {
    int c = colp[e], r = rowp[e];
    int p = off[c] + atomicAdd(&cursor[c], 1);
    ssrc[p] = r;
    sw[p] = dis[r] * dis[c];
  }
}

// ---------------- W pre-pack into MFMA B-fragment order (bf16) ----------------
// Fragment (nt, ks): lane l holds 8 bf16 of B[k = ks*32 + (l>>4)*8 + i][n = nt*16 + (l&15)]

__global__ void k_packW1(const float* __restrict__ W, ushort* __restrict__ Wp) {
  int t = blockIdx.x * 256 + threadIdx.x;  // < 8*8*64
  if (t >= 8 * 8 * 64) return;
  int l = t & 63, ks = (t >> 6) & 7, nt = t >> 9;
  int k0 = ks * 32 + (l >> 4) * 8;
  int n = nt * 16 + (l & 15);
  ushort* dst = Wp + (size_t)t * 8;
#pragma unroll
  for (int i = 0; i < 8; i++) dst[i] = f2bf(W[(k0 + i) * DHID + n]);
}

__global__ void k_packW2(const float* __restrict__ W, ushort* __restrict__ Wp) {
  int t = blockIdx.x * 256 + threadIdx.x;  // < 4*4*64
  if (t >= 4 * 4 * 64) return;
  int l = t & 63, ks = (t >> 6) & 3, nt = t >> 8;
  int k0 = ks * 32 + (l >> 4) * 8;
  int n = nt * 16 + (l & 15);
  ushort* dst = Wp + (size_t)t * 8;
#pragma unroll
  for (int i = 0; i < 8; i++) dst[i] = f2bf(W[(k0 + i) * DOUT + n]);
}

// ---------------- GEMM1 (MFMA bf16): h1[N,128]bf16 = x[N,256]f32 @ W1 ----------------
// 256 thr = 4 waves; wave owns 16 rows, all 8 n-tiles. K = 256 = 8 steps of 32.

__global__ __launch_bounds__(256) void k_gemm1(const float* __restrict__ x,
                                               const ushort* __restrict__ Wp,
                                               ushort* __restrict__ h1) {
  __shared__ ushort cs[4][16][DHID];  // 16 KB
  int w = threadIdx.x >> 6, l = threadIdx.x & 63;
  int row0 = blockIdx.x * 64 + w * 16;
  bool valid = (row0 < N_NODES);  // N % 16 == 0, so waves are all-or-nothing
  if (valid) {
    f32x4 acc[8];
#pragma unroll
    for (int i = 0; i < 8; i++) acc[i] = (f32x4)(0.f);
    int arow = row0 + (l & 15);
    const float4* xg = (const float4*)(x + (size_t)arow * DIN) + (l >> 4) * 2;
    const bf16x8* wp = (const bf16x8*)Wp;
#pragma unroll
    for (int ks = 0; ks < 8; ks++) {
      float4 a0 = xg[ks * 8];
      float4 a1 = xg[ks * 8 + 1];
      bf16x8 af;
      af[0] = (short)f2bf(a0.x); af[1] = (short)f2bf(a0.y);
      af[2] = (short)f2bf(a0.z); af[3] = (short)f2bf(a0.w);
      af[4] = (short)f2bf(a1.x); af[5] = (short)f2bf(a1.y);
      af[6] = (short)f2bf(a1.z); af[7] = (short)f2bf(a1.w);
#pragma unroll
      for (int nt = 0; nt < 8; nt++) {
        bf16x8 bf = wp[(nt * 8 + ks) * 64 + l];
        acc[nt] = __builtin_amdgcn_mfma_f32_16x16x32_bf16(af, bf, acc[nt], 0, 0, 0);
      }
    }
    // C: D[row=(l>>4)*4+r][col=nt*16+(l&15)] -> LDS (bf16)
#pragma unroll
    for (int nt = 0; nt < 8; nt++)
#pragma unroll
      for (int r = 0; r < 4; r++)
        cs[w][(l >> 4) * 4 + r][nt * 16 + (l & 15)] = f2bf(acc[nt][r]);
  }
  __syncthreads();
  if (valid) {
    const uint4* s4 = (const uint4*)&cs[w][l >> 2][(l & 3) * 32];
    uint4* dst = (uint4*)(h1 + (size_t)(row0 + (l >> 2)) * DHID + (l & 3) * 32);
    dst[0] = s4[0]; dst[1] = s4[1]; dst[2] = s4[2]; dst[3] = s4[3];
  }
}

// ---------------- GEMM2 (MFMA bf16): h2[N,64]bf16 = a1[N,128]bf16 @ W2 ----------------

__global__ __launch_bounds__(256) void k_gemm2(const ushort* __restrict__ a1,
                                               const ushort* __restrict__ Wp,
                                               ushort* __restrict__ h2) {
  __shared__ ushort cs[4][16][DOUT];  // 8 KB
  int w = threadIdx.x >> 6, l = threadIdx.x & 63;
  int row0 = blockIdx.x * 64 + w * 16;
  bool valid = (row0 < N_NODES);
  if (valid) {
    f32x4 acc[4];
#pragma unroll
    for (int i = 0; i < 4; i++) acc[i] = (f32x4)(0.f);
    int arow = row0 + (l & 15);
    const bf16x8* ag = (const bf16x8*)(a1 + (size_t)arow * DHID) + (l >> 4);
    const bf16x8* wp = (const bf16x8*)Wp;
#pragma unroll
    for (int ks = 0; ks < 4; ks++) {
      bf16x8 af = ag[ks * 4];
#pragma unroll
      for (int nt = 0; nt < 4; nt++) {
        bf16x8 bf = wp[(nt * 4 + ks) * 64 + l];
        acc[nt] = __builtin_amdgcn_mfma_f32_16x16x32_bf16(af, bf, acc[nt], 0, 0, 0);
      }
    }
#pragma unroll
    for (int nt = 0; nt < 4; nt++)
#pragma unroll
      for (int r = 0; r < 4; r++)
        cs[w][(l >> 4) * 4 + r][nt * 16 + (l & 15)] = f2bf(acc[nt][r]);
  }
  __syncthreads();
  if (valid) {
    const uint4* s4 = (const uint4*)&cs[w][l >> 2][(l & 3) * 16];
    uint4* dst = (uint4*)(h2 + (size_t)(row0 + (l >> 2)) * DOUT + (l & 3) * 16);
    dst[0] = s4[0]; dst[1] = s4[1];
  }
}

// ---------------- aggregation layer 1 (wave/node, h1 bf16, out a1 bf16) ----------------

__global__ __launch_bounds__(256) void k_agg1(const uint* __restrict__ h1,
                                              const int* __restrict__ off,
                                              const int* __restrict__ src,
                                              const float* __restrict__ ew,
                                              const float* __restrict__ dis,
                                              const float* __restrict__ b1,
                                              uint* __restrict__ a1) {
  int wid  = (blockIdx.x * 256 + threadIdx.x) >> 6;
  int lane = threadIdx.x & 63;
  if (wid >= N_NODES) return;
  float d = dis[wid];
  float d2 = d * d;
  uint hv = h1[(size_t)wid * 64 + lane];
  float ax = __uint_as_float(hv << 16) * d2;
  float ay = __uint_as_float(hv & 0xffff0000u) * d2;
  int o0 = __builtin_amdgcn_readfirstlane(off[wid]);
  int o1 = __builtin_amdgcn_readfirstlane(off[wid + 1]);
  int e = o0;
  for (; e + 4 <= o1; e += 4) {
    int s0 = src[e], s1 = src[e + 1], s2 = src[e + 2], s3 = src[e + 3];
    float w0 = ew[e], w1 = ew[e + 1], w2 = ew[e + 2], w3 = ew[e + 3];
    uint v0 = h1[(size_t)s0 * 64 + lane];
    uint v1 = h1[(size_t)s1 * 64 + lane];
    uint v2 = h1[(size_t)s2 * 64 + lane];
    uint v3 = h1[(size_t)s3 * 64 + lane];
    ax = fmaf(__uint_as_float(v0 << 16), w0, ax);
    ay = fmaf(__uint_as_float(v0 & 0xffff0000u), w0, ay);
    ax = fmaf(__uint_as_float(v1 << 16), w1, ax);
    ay = fmaf(__uint_as_float(v1 & 0xffff0000u), w1, ay);
    ax = fmaf(__uint_as_float(v2 << 16), w2, ax);
    ay = fmaf(__uint_as_float(v2 & 0xffff0000u), w2, ay);
    ax = fmaf(__uint_as_float(v3 << 16), w3, ax);
    ay = fmaf(__uint_as_float(v3 & 0xffff0000u), w3, ay);
  }
  for (; e < o1; e++) {
    int s = src[e];
    float w0 = ew[e];
    uint v0 = h1[(size_t)s * 64 + lane];
    ax = fmaf(__uint_as_float(v0 << 16), w0, ax);
    ay = fmaf(__uint_as_float(v0 & 0xffff0000u), w0, ay);
  }
  float2 bb = ((const float2*)b1)[lane];
  float rx = fmaxf(ax + bb.x, 0.f);
  float ry = fmaxf(ay + bb.y, 0.f);
  a1[(size_t)wid * 64 + lane] = (uint)f2bf(rx) | ((uint)f2bf(ry) << 16);
}

// -------- aggregation layer 2 (h2 bf16) + bias + log_softmax -> f32 out --------

__global__ __launch_bounds__(256) void k_agg2(const ushort* __restrict__ h2,
                                              const int* __restrict__ off,
                                              const int* __restrict__ src,
                                              const float* __restrict__ ew,
                                              const float* __restrict__ dis,
                                              const float* __restrict__ b2,
                                              float* __restrict__ out) {
  int wid  = (blockIdx.x * 256 + threadIdx.x) >> 6;
  int lane = threadIdx.x & 63;
  if (wid >= N_NODES) return;
  float d = dis[wid];
  float acc = bf2f(h2[(size_t)wid * 64 + lane]) * d * d;
  int o0 = __builtin_amdgcn_readfirstlane(off[wid]);
  int o1 = __builtin_amdgcn_readfirstlane(off[wid + 1]);
  int e = o0;
  for (; e + 4 <= o1; e += 4) {
    int s0 = src[e], s1 = src[e + 1], s2 = src[e + 2], s3 = src[e + 3];
    float w0 = ew[e], w1 = ew[e + 1], w2 = ew[e + 2], w3 = ew[e + 3];
    float v0 = bf2f(h2[(size_t)s0 * 64 + lane]);
    float v1 = bf2f(h2[(size_t)s1 * 64 + lane]);
    float v2 = bf2f(h2[(size_t)s2 * 64 + lane]);
    float v3 = bf2f(h2[(size_t)s3 * 64 + lane]);
    acc = fmaf(v0, w0, acc);
    acc = fmaf(v1, w1, acc);
    acc = fmaf(v2, w2, acc);
    acc = fmaf(v3, w3, acc);
  }
  for (; e < o1; e++) {
    acc = fmaf(bf2f(h2[(size_t)src[e] * 64 + lane]), ew[e], acc);
  }
  float v = acc + b2[lane];
  float m = v;
#pragma unroll
  for (int sft = 32; sft >= 1; sft >>= 1) m = fmaxf(m, __shfl_xor(m, sft, 64));
  float ex = expf(v - m);
  float sum = ex;
#pragma unroll
  for (int sft = 32; sft >= 1; sft >>= 1) sum += __shfl_xor(sum, sft, 64);
  out[(size_t)wid * 64 + lane] = v - m - logf(sum);
}

// ---------------- launch ----------------

extern "C" void kernel_launch(void* const* d_in, const int* in_sizes, int n_in,
                              void* d_out, int out_size, void* d_ws, size_t ws_size,
                              hipStream_t stream) {
  const float* x  = (const float*)d_in[0];
  const int*   ei = (const int*)d_in[1];
  const float* W1 = (const float*)d_in[2];
  const float* b1 = (const float*)d_in[3];
  const float* W2 = (const float*)d_in[4];
  const float* b2 = (const float*)d_in[5];
  float* out = (float*)d_out;
  const int* rowp = ei;            // sources
  const int* colp = ei + N_EDGES;  // destinations

  char* p = (char*)d_ws;
  size_t o = 0;
  auto alloc = [&](size_t bytes) -> void* {
    void* r = p + o;
    o = (o + bytes + 255) & ~(size_t)255;
    return r;
  };
  int*    cnt    = (int*)alloc((size_t)N_NODES * 4);
  int*    cursor = (int*)alloc((size_t)N_NODES * 4);
  int*    off    = (int*)alloc((size_t)(N_NODES + 1) * 4);
  int*    bsum   = (int*)alloc(256 * 4);
  float*  dis    = (float*)alloc((size_t)N_NODES * 4);
  int*    ssrc   = (int*)alloc((size_t)N_EDGES * 4);
  float*  swt    = (float*)alloc((size_t)N_EDGES * 4);
  ushort* Wp1    = (ushort*)alloc((size_t)8 * 8 * 64 * 8 * 2);   // 64 KB
  ushort* Wp2    = (ushort*)alloc((size_t)4 * 4 * 64 * 8 * 2);   // 16 KB
  ushort* h1     = (ushort*)alloc((size_t)N_NODES * DHID * 2);   // 25.6 MB bf16
  ushort* a1     = (ushort*)alloc((size_t)N_NODES * DHID * 2);   // 25.6 MB bf16
  ushort* h2     = h1;  // h1 dead after k_agg1

  hipMemsetAsync(cnt, 0, (size_t)N_NODES * 4, stream);
  hipMemsetAsync(cursor, 0, (size_t)N_NODES * 4, stream);

  k_count<<<(N_EDGES + 255) / 256, 256, 0, stream>>>(colp, cnt);
  k_dis<<<(N_NODES + 255) / 256, 256, 0, stream>>>(cnt, dis);
  k_scan1<<<(N_NODES + 1023) / 1024, 256, 0, stream>>>(cnt, off, bsum);
  k_scan2<<<1, 256, 0, stream>>>(bsum, off);
  k_scan3<<<(N_NODES + 255) / 256, 256, 0, stream>>>(off, bsum);
  k_scatter<<<(N_EDGES + 255) / 256, 256, 0, stream>>>(rowp, colp, dis, off, cursor, ssrc, swt);
  k_packW1<<<16, 256, 0, stream>>>(W1, Wp1);
  k_packW2<<<4, 256, 0, stream>>>(W2, Wp2);
  k_gemm1<<<(N_NODES + 63) / 64, 256, 0, stream>>>(x, Wp1, h1);
  k_agg1<<<(N_NODES + 3) / 4, 256, 0, stream>>>((const uint*)h1, off, ssrc, swt, dis, b1, (uint*)a1);
  k_gemm2<<<(N_NODES + 63) / 64, 256, 0, stream>>>(a1, Wp2, h2);
  k_agg2<<<(N_NODES + 3) / 4, 256, 0, stream>>>(h2, off, ssrc, swt, dis, b2, out);
}

// Round 3
// 300.144 us; speedup vs baseline: 2.1506x; 1.1895x over previous
//
#include <hip/hip_runtime.h>

#define N_NODES 100000
#define N_EDGES 1600000
#define DIN 256
#define DHID 128
#define DOUT 64

#define BSHIFT 9
#define NBUCKET 196   // ceil(100000 / 512)
#define CHUNK 8192
#define NCHUNK 196    // ceil(1600000 / 8192)

typedef __attribute__((ext_vector_type(8))) short bf16x8;
typedef __attribute__((ext_vector_type(4))) float f32x4;

static __device__ __forceinline__ ushort f2bf(float f) {
  union { float f; uint u; } a; a.f = f;
  uint u = a.u;
  uint r = u + 0x7fffu + ((u >> 16) & 1u);  // RNE
  return (ushort)(r >> 16);
}
static __device__ __forceinline__ float bf2f(ushort h) {
  return __uint_as_float(((uint)h) << 16);
}

// ------------- B1: per-chunk bucket histogram + per-node degree count -------------

__global__ __launch_bounds__(256) void k_histcount(const int* __restrict__ colp,
                                                   int* __restrict__ cnt,
                                                   int* __restrict__ cntmat) {
  __shared__ int h[NBUCKET];
  int c = blockIdx.x;
  for (int i = threadIdx.x; i < NBUCKET; i += 256) h[i] = 0;
  __syncthreads();
  int e0 = c * CHUNK, e1 = min(e0 + CHUNK, N_EDGES);
  for (int e = e0 + threadIdx.x; e < e1; e += 256) {
    int dst = colp[e];
    atomicAdd(&h[dst >> BSHIFT], 1);
    atomicAdd(&cnt[dst], 1);
  }
  __syncthreads();
  for (int i = threadIdx.x; i < NBUCKET; i += 256)
    cntmat[c * NBUCKET + i] = h[i];
}

__global__ void k_dis(const int* __restrict__ cnt, float* __restrict__ dis) {
  int i = blockIdx.x * 256 + threadIdx.x;
  if (i < N_NODES) dis[i] = rsqrtf((float)cnt[i] + 1.0f);  // +1 self-loop
}

// ---------------- exclusive scan over cnt -> off ----------------

__global__ void k_scan1(const int* __restrict__ cnt, int* __restrict__ off,
                        int* __restrict__ bsum) {
  __shared__ int s[256];
  int t = threadIdx.x;
  int base = blockIdx.x * 1024 + t * 4;
  int v0 = (base + 0 < N_NODES) ? cnt[base + 0] : 0;
  int v1 = (base + 1 < N_NODES) ? cnt[base + 1] : 0;
  int v2 = (base + 2 < N_NODES) ? cnt[base + 2] : 0;
  int v3 = (base + 3 < N_NODES) ? cnt[base + 3] : 0;
  int mysum = v0 + v1 + v2 + v3;
  s[t] = mysum;
  __syncthreads();
  for (int d = 1; d < 256; d <<= 1) {
    int y = (t >= d) ? s[t - d] : 0;
    __syncthreads();
    s[t] += y;
    __syncthreads();
  }
  int run = s[t] - mysum;
  if (base + 0 < N_NODES) off[base + 0] = run; run += v0;
  if (base + 1 < N_NODES) off[base + 1] = run; run += v1;
  if (base + 2 < N_NODES) off[base + 2] = run; run += v2;
  if (base + 3 < N_NODES) off[base + 3] = run;
  if (t == 255) bsum[blockIdx.x] = s[255];
}

__global__ void k_scan2(int* __restrict__ bsum, int* __restrict__ off) {
  __shared__ int s[256];
  int t = threadIdx.x;
  const int nb = (N_NODES + 1023) / 1024;
  int v = (t < nb) ? bsum[t] : 0;
  s[t] = v;
  __syncthreads();
  for (int d = 1; d < 256; d <<= 1) {
    int y = (t >= d) ? s[t - d] : 0;
    __syncthreads();
    s[t] += y;
    __syncthreads();
  }
  if (t < nb) bsum[t] = s[t] - v;
  if (t == 255) off[N_NODES] = s[255];
}

__global__ void k_scan3(int* __restrict__ off, const int* __restrict__ bsum) {
  int i = blockIdx.x * 256 + threadIdx.x;
  if (i < N_NODES) off[i] += bsum[i >> 10];
}

// ------------- B2: per-(chunk,bucket) base offsets -------------

__global__ void k_chunkbase(const int* __restrict__ cntmat, const int* __restrict__ off,
                            int* __restrict__ basemat) {
  int b = threadIdx.x;
  if (b >= NBUCKET) return;
  int running = off[b << BSHIFT];
  for (int c = 0; c < NCHUNK; c++) {
    basemat[c * NBUCKET + b] = running;
    running += cntmat[c * NBUCKET + b];
  }
}

// ------------- B3: bin edges into bucket-contiguous segments -------------

__global__ __launch_bounds__(256) void k_binscatter(const int* __restrict__ rowp,
                                                    const int* __restrict__ colp,
                                                    const int* __restrict__ basemat,
                                                    int2* __restrict__ packed) {
  __shared__ int lcur[NBUCKET];
  int c = blockIdx.x;
  for (int i = threadIdx.x; i < NBUCKET; i += 256)
    lcur[i] = basemat[c * NBUCKET + i];
  __syncthreads();
  int e0 = c * CHUNK, e1 = min(e0 + CHUNK, N_EDGES);
  for (int e = e0 + threadIdx.x; e < e1; e += 256) {
    int dst = colp[e], src = rowp[e];
    int pos = atomicAdd(&lcur[dst >> BSHIFT], 1);
    packed[pos] = make_int2(src, dst);
  }
}

// ------------- C: per-bucket counting sort into final CSR -------------

__global__ __launch_bounds__(256) void k_localsort(const int2* __restrict__ packed,
                                                   const int* __restrict__ off,
                                                   int* __restrict__ ssrc) {
  __shared__ int lcur[512];
  int b = blockIdx.x;
  int node0 = b << BSHIFT;
  int node1 = min(node0 + 512, N_NODES);
  for (int i = threadIdx.x; i < 512; i += 256) lcur[i] = 0;
  __syncthreads();
  int r0 = off[node0], r1 = off[node1];
  for (int r = r0 + threadIdx.x; r < r1; r += 256) {
    int2 sd = packed[r];
    int pos = off[sd.y] + atomicAdd(&lcur[sd.y - node0], 1);
    ssrc[pos] = sd.x;
  }
}

// ---------------- W pre-pack into MFMA B-fragment order (bf16) ----------------

__global__ void k_packW1(const float* __restrict__ W, ushort* __restrict__ Wp) {
  int t = blockIdx.x * 256 + threadIdx.x;  // < 8*8*64
  if (t >= 8 * 8 * 64) return;
  int l = t & 63, ks = (t >> 6) & 7, nt = t >> 9;
  int k0 = ks * 32 + (l >> 4) * 8;
  int n = nt * 16 + (l & 15);
  ushort* dst = Wp + (size_t)t * 8;
#pragma unroll
  for (int i = 0; i < 8; i++) dst[i] = f2bf(W[(k0 + i) * DHID + n]);
}

__global__ void k_packW2(const float* __restrict__ W, ushort* __restrict__ Wp) {
  int t = blockIdx.x * 256 + threadIdx.x;  // < 4*4*64
  if (t >= 4 * 4 * 64) return;
  int l = t & 63, ks = (t >> 6) & 3, nt = t >> 8;
  int k0 = ks * 32 + (l >> 4) * 8;
  int n = nt * 16 + (l & 15);
  ushort* dst = Wp + (size_t)t * 8;
#pragma unroll
  for (int i = 0; i < 8; i++) dst[i] = f2bf(W[(k0 + i) * DOUT + n]);
}

// ---------------- GEMM1 (MFMA bf16): h1[N,128]bf16 = x[N,256]f32 @ W1 ----------------

__global__ __launch_bounds__(256) void k_gemm1(const float* __restrict__ x,
                                               const ushort* __restrict__ Wp,
                                               ushort* __restrict__ h1) {
  __shared__ ushort cs[4][16][DHID];  // 16 KB
  int w = threadIdx.x >> 6, l = threadIdx.x & 63;
  int row0 = blockIdx.x * 64 + w * 16;
  bool valid = (row0 < N_NODES);  // N % 16 == 0
  if (valid) {
    f32x4 acc[8];
#pragma unroll
    for (int i = 0; i < 8; i++) acc[i] = (f32x4)(0.f);
    int arow = row0 + (l & 15);
    const float4* xg = (const float4*)(x + (size_t)arow * DIN) + (l >> 4) * 2;
    const bf16x8* wp = (const bf16x8*)Wp;
#pragma unroll
    for (int ks = 0; ks < 8; ks++) {
      float4 a0 = xg[ks * 8];
      float4 a1 = xg[ks * 8 + 1];
      bf16x8 af;
      af[0] = (short)f2bf(a0.x); af[1] = (short)f2bf(a0.y);
      af[2] = (short)f2bf(a0.z); af[3] = (short)f2bf(a0.w);
      af[4] = (short)f2bf(a1.x); af[5] = (short)f2bf(a1.y);
      af[6] = (short)f2bf(a1.z); af[7] = (short)f2bf(a1.w);
#pragma unroll
      for (int nt = 0; nt < 8; nt++) {
        bf16x8 bf = wp[(nt * 8 + ks) * 64 + l];
        acc[nt] = __builtin_amdgcn_mfma_f32_16x16x32_bf16(af, bf, acc[nt], 0, 0, 0);
      }
    }
#pragma unroll
    for (int nt = 0; nt < 8; nt++)
#pragma unroll
      for (int r = 0; r < 4; r++)
        cs[w][(l >> 4) * 4 + r][nt * 16 + (l & 15)] = f2bf(acc[nt][r]);
  }
  __syncthreads();
  if (valid) {
    const uint4* s4 = (const uint4*)&cs[w][l >> 2][(l & 3) * 32];
    uint4* dst = (uint4*)(h1 + (size_t)(row0 + (l >> 2)) * DHID + (l & 3) * 32);
    dst[0] = s4[0]; dst[1] = s4[1]; dst[2] = s4[2]; dst[3] = s4[3];
  }
}

// ---------------- GEMM2 (MFMA bf16): h2[N,64]bf16 = a1[N,128]bf16 @ W2 ----------------

__global__ __launch_bounds__(256) void k_gemm2(const ushort* __restrict__ a1,
                                               const ushort* __restrict__ Wp,
                                               ushort* __restrict__ h2) {
  __shared__ ushort cs[4][16][DOUT];  // 8 KB
  int w = threadIdx.x >> 6, l = threadIdx.x & 63;
  int row0 = blockIdx.x * 64 + w * 16;
  bool valid = (row0 < N_NODES);
  if (valid) {
    f32x4 acc[4];
#pragma unroll
    for (int i = 0; i < 4; i++) acc[i] = (f32x4)(0.f);
    int arow = row0 + (l & 15);
    const bf16x8* ag = (const bf16x8*)(a1 + (size_t)arow * DHID) + (l >> 4);
    const bf16x8* wp = (const bf16x8*)Wp;
#pragma unroll
    for (int ks = 0; ks < 4; ks++) {
      bf16x8 af = ag[ks * 4];
#pragma unroll
      for (int nt = 0; nt < 4; nt++) {
        bf16x8 bf = wp[(nt * 4 + ks) * 64 + l];
        acc[nt] = __builtin_amdgcn_mfma_f32_16x16x32_bf16(af, bf, acc[nt], 0, 0, 0);
      }
    }
#pragma unroll
    for (int nt = 0; nt < 4; nt++)
#pragma unroll
      for (int r = 0; r < 4; r++)
        cs[w][(l >> 4) * 4 + r][nt * 16 + (l & 15)] = f2bf(acc[nt][r]);
  }
  __syncthreads();
  if (valid) {
    const uint4* s4 = (const uint4*)&cs[w][l >> 2][(l & 3) * 16];
    uint4* dst = (uint4*)(h2 + (size_t)(row0 + (l >> 2)) * DOUT + (l & 3) * 16);
    dst[0] = s4[0]; dst[1] = s4[1];
  }
}

// ------- aggregation layer 1 (wave/node): w = dis[src]*dis[dst] on the fly -------

__global__ __launch_bounds__(256) void k_agg1(const uint* __restrict__ h1,
                                              const int* __restrict__ off,
                                              const int* __restrict__ src,
                                              const float* __restrict__ dis,
                                              const float* __restrict__ b1,
                                              uint* __restrict__ a1) {
  int wid  = (blockIdx.x * 256 + threadIdx.x) >> 6;
  int lane = threadIdx.x & 63;
  if (wid >= N_NODES) return;
  float d = dis[wid];
  float d2 = d * d;
  uint hv = h1[(size_t)wid * 64 + lane];
  float ax = __uint_as_float(hv << 16) * d2;
  float ay = __uint_as_float(hv & 0xffff0000u) * d2;
  int o0 = __builtin_amdgcn_readfirstlane(off[wid]);
  int o1 = __builtin_amdgcn_readfirstlane(off[wid + 1]);
  int e = o0;
  for (; e + 4 <= o1; e += 4) {
    int s0 = src[e], s1 = src[e + 1], s2 = src[e + 2], s3 = src[e + 3];
    float w0 = dis[s0] * d, w1 = dis[s1] * d, w2 = dis[s2] * d, w3 = dis[s3] * d;
    uint v0 = h1[(size_t)s0 * 64 + lane];
    uint v1 = h1[(size_t)s1 * 64 + lane];
    uint v2 = h1[(size_t)s2 * 64 + lane];
    uint v3 = h1[(size_t)s3 * 64 + lane];
    ax = fmaf(__uint_as_float(v0 << 16), w0, ax);
    ay = fmaf(__uint_as_float(v0 & 0xffff0000u), w0, ay);
    ax = fmaf(__uint_as_float(v1 << 16), w1, ax);
    ay = fmaf(__uint_as_float(v1 & 0xffff0000u), w1, ay);
    ax = fmaf(__uint_as_float(v2 << 16), w2, ax);
    ay = fmaf(__uint_as_float(v2 & 0xffff0000u), w2, ay);
    ax = fmaf(__uint_as_float(v3 << 16), w3, ax);
    ay = fmaf(__uint_as_float(v3 & 0xffff0000u), w3, ay);
  }
  for (; e < o1; e++) {
    int s = src[e];
    float w0 = dis[s] * d;
    uint v0 = h1[(size_t)s * 64 + lane];
    ax = fmaf(__uint_as_float(v0 << 16), w0, ax);
    ay = fmaf(__uint_as_float(v0 & 0xffff0000u), w0, ay);
  }
  float2 bb = ((const float2*)b1)[lane];
  float rx = fmaxf(ax + bb.x, 0.f);
  float ry = fmaxf(ay + bb.y, 0.f);
  a1[(size_t)wid * 64 + lane] = (uint)f2bf(rx) | ((uint)f2bf(ry) << 16);
}

// -------- aggregation layer 2 + bias + log_softmax -> f32 out --------

__global__ __launch_bounds__(256) void k_agg2(const ushort* __restrict__ h2,
                                              const int* __restrict__ off,
                                              const int* __restrict__ src,
                                              const float* __restrict__ dis,
                                              const float* __restrict__ b2,
                                              float* __restrict__ out) {
  int wid  = (blockIdx.x * 256 + threadIdx.x) >> 6;
  int lane = threadIdx.x & 63;
  if (wid >= N_NODES) return;
  float d = dis[wid];
  float acc = bf2f(h2[(size_t)wid * 64 + lane]) * d * d;
  int o0 = __builtin_amdgcn_readfirstlane(off[wid]);
  int o1 = __builtin_amdgcn_readfirstlane(off[wid + 1]);
  int e = o0;
  for (; e + 4 <= o1; e += 4) {
    int s0 = src[e], s1 = src[e + 1], s2 = src[e + 2], s3 = src[e + 3];
    float w0 = dis[s0] * d, w1 = dis[s1] * d, w2 = dis[s2] * d, w3 = dis[s3] * d;
    float v0 = bf2f(h2[(size_t)s0 * 64 + lane]);
    float v1 = bf2f(h2[(size_t)s1 * 64 + lane]);
    float v2 = bf2f(h2[(size_t)s2 * 64 + lane]);
    float v3 = bf2f(h2[(size_t)s3 * 64 + lane]);
    acc = fmaf(v0, w0, acc);
    acc = fmaf(v1, w1, acc);
    acc = fmaf(v2, w2, acc);
    acc = fmaf(v3, w3, acc);
  }
  for (; e < o1; e++) {
    acc = fmaf(bf2f(h2[(size_t)src[e] * 64 + lane]), dis[src[e]] * d, acc);
  }
  float v = acc + b2[lane];
  float m = v;
#pragma unroll
  for (int sft = 32; sft >= 1; sft >>= 1) m = fmaxf(m, __shfl_xor(m, sft, 64));
  float ex = expf(v - m);
  float sum = ex;
#pragma unroll
  for (int sft = 32; sft >= 1; sft >>= 1) sum += __shfl_xor(sum, sft, 64);
  out[(size_t)wid * 64 + lane] = v - m - logf(sum);
}

// ---------------- launch ----------------

extern "C" void kernel_launch(void* const* d_in, const int* in_sizes, int n_in,
                              void* d_out, int out_size, void* d_ws, size_t ws_size,
                              hipStream_t stream) {
  const float* x  = (const float*)d_in[0];
  const int*   ei = (const int*)d_in[1];
  const float* W1 = (const float*)d_in[2];
  const float* b1 = (const float*)d_in[3];
  const float* W2 = (const float*)d_in[4];
  const float* b2 = (const float*)d_in[5];
  float* out = (float*)d_out;
  const int* rowp = ei;            // sources
  const int* colp = ei + N_EDGES;  // destinations

  char* p = (char*)d_ws;
  size_t o = 0;
  auto alloc = [&](size_t bytes) -> void* {
    void* r = p + o;
    o = (o + bytes + 255) & ~(size_t)255;
    return r;
  };
  int*    cnt    = (int*)alloc((size_t)N_NODES * 4);
  int*    off    = (int*)alloc((size_t)(N_NODES + 1) * 4);
  int*    bsum   = (int*)alloc(256 * 4);
  float*  dis    = (float*)alloc((size_t)N_NODES * 4);
  int*    cntmat = (int*)alloc((size_t)NCHUNK * NBUCKET * 4);
  int*    basemat= (int*)alloc((size_t)NCHUNK * NBUCKET * 4);
  int2*   packed = (int2*)alloc((size_t)N_EDGES * 8);
  int*    ssrc   = (int*)alloc((size_t)N_EDGES * 4);
  ushort* Wp1    = (ushort*)alloc((size_t)8 * 8 * 64 * 8 * 2);
  ushort* Wp2    = (ushort*)alloc((size_t)4 * 4 * 64 * 8 * 2);
  ushort* h1     = (ushort*)alloc((size_t)N_NODES * DHID * 2);
  ushort* a1     = (ushort*)alloc((size_t)N_NODES * DHID * 2);
  ushort* h2     = h1;  // h1 dead after k_agg1

  hipMemsetAsync(cnt, 0, (size_t)N_NODES * 4, stream);

  k_histcount<<<NCHUNK, 256, 0, stream>>>(colp, cnt, cntmat);
  k_dis<<<(N_NODES + 255) / 256, 256, 0, stream>>>(cnt, dis);
  k_scan1<<<(N_NODES + 1023) / 1024, 256, 0, stream>>>(cnt, off, bsum);
  k_scan2<<<1, 256, 0, stream>>>(bsum, off);
  k_scan3<<<(N_NODES + 255) / 256, 256, 0, stream>>>(off, bsum);
  k_chunkbase<<<1, 256, 0, stream>>>(cntmat, off, basemat);
  k_binscatter<<<NCHUNK, 256, 0, stream>>>(rowp, colp, basemat, packed);
  k_localsort<<<NBUCKET, 256, 0, stream>>>(packed, off, ssrc);
  k_packW1<<<16, 256, 0, stream>>>(W1, Wp1);
  k_packW2<<<4, 256, 0, stream>>>(W2, Wp2);
  k_gemm1<<<(N_NODES + 63) / 64, 256, 0, stream>>>(x, Wp1, h1);
  k_agg1<<<(N_NODES + 3) / 4, 256, 0, stream>>>((const uint*)h1, off, ssrc, dis, b1, (uint*)a1);
  k_gemm2<<<(N_NODES + 63) / 64, 256, 0, stream>>>(a1, Wp2, h2);
  k_agg2<<<(N_NODES + 3) / 4, 256, 0, stream>>>(h2, off, ssrc, dis, b2, out);
}

// Round 5
// 231.965 us; speedup vs baseline: 2.7827x; 1.2939x over previous
//
#include <hip/hip_runtime.h>

#define N_NODES 100000
#define N_EDGES 1600000
#define DIN 256
#define DHID 128
#define DOUT 64

#define BSHIFT 9
#define NBUCKET 196                 // ceil(100000 / 512)
#define CHUNK 4096
#define NCHUNK ((N_EDGES + CHUNK - 1) / CHUNK)  // 391

typedef __attribute__((ext_vector_type(8))) short bf16x8;
typedef __attribute__((ext_vector_type(4))) float f32x4;

static __device__ __forceinline__ ushort f2bf(float f) {
  union { float f; uint u; } a; a.f = f;
  uint u = a.u;
  uint r = u + 0x7fffu + ((u >> 16) & 1u);  // RNE
  return (ushort)(r >> 16);
}
static __device__ __forceinline__ float bf2f(ushort h) {
  return __uint_as_float(((uint)h) << 16);
}

// ------------- B1: per-chunk bucket histogram (LDS atomics only) -------------

__global__ __launch_bounds__(256) void k_hist(const int* __restrict__ colp,
                                              int* __restrict__ cntmat) {
  __shared__ int h[NBUCKET];
  int c = blockIdx.x;
  for (int i = threadIdx.x; i < NBUCKET; i += 256) h[i] = 0;
  __syncthreads();
  int e0 = c * CHUNK, e1 = min(e0 + CHUNK, N_EDGES);
  for (int e = e0 + threadIdx.x; e < e1; e += 256)
    atomicAdd(&h[colp[e] >> BSHIFT], 1);
  __syncthreads();
  for (int i = threadIdx.x; i < NBUCKET; i += 256)
    cntmat[c * NBUCKET + i] = h[i];
}

// ------------- bucket totals (one block per bucket) -------------

__global__ __launch_bounds__(256) void k_buckettot(const int* __restrict__ cntmat,
                                                   int* __restrict__ btot) {
  __shared__ int s[256];
  int b = blockIdx.x, t = threadIdx.x;
  int sum = 0;
  for (int c = t; c < NCHUNK; c += 256) sum += cntmat[c * NBUCKET + b];
  s[t] = sum;
  __syncthreads();
  for (int d = 128; d > 0; d >>= 1) {
    if (t < d) s[t] += s[t + d];
    __syncthreads();
  }
  if (t == 0) btot[b] = s[0];
}

// ------------- exclusive scan over 196 bucket totals -------------

__global__ void k_bucketscan(const int* __restrict__ btot, int* __restrict__ bbase) {
  __shared__ int s[256];
  int t = threadIdx.x;
  int v = (t < NBUCKET) ? btot[t] : 0;
  s[t] = v;
  __syncthreads();
  for (int d = 1; d < 256; d <<= 1) {
    int y = (t >= d) ? s[t - d] : 0;
    __syncthreads();
    s[t] += y;
    __syncthreads();
  }
  if (t < NBUCKET) bbase[t] = s[t] - v;
  if (t == 0) bbase[NBUCKET] = N_EDGES;
}

// ------------- per-(chunk,bucket) bases: wave-per-bucket prefix over chunks -------------

__global__ __launch_bounds__(256) void k_chunkpfx(const int* __restrict__ cntmat,
                                                  const int* __restrict__ bbase,
                                                  int* __restrict__ basemat) {
  int wid = blockIdx.x * 4 + (threadIdx.x >> 6);
  int lane = threadIdx.x & 63;
  if (wid >= NBUCKET) return;
  int carry = bbase[wid];
  const int NT = (NCHUNK + 63) / 64;
  for (int tt = 0; tt < NT; tt++) {
    int c = tt * 64 + lane;
    int v = (c < NCHUNK) ? cntmat[c * NBUCKET + wid] : 0;
    int incl = v;
#pragma unroll
    for (int d = 1; d < 64; d <<= 1) {
      int y = __shfl_up(incl, d, 64);
      if (lane >= d) incl += y;
    }
    if (c < NCHUNK) basemat[c * NBUCKET + wid] = carry + incl - v;
    carry += __shfl(incl, 63, 64);
  }
}

// ------------- B3: bin edges into bucket-contiguous segments -------------

__global__ __launch_bounds__(256) void k_binscatter(const int* __restrict__ rowp,
                                                    const int* __restrict__ colp,
                                                    const int* __restrict__ basemat,
                                                    int2* __restrict__ packed) {
  __shared__ int lcur[NBUCKET];
  int c = blockIdx.x;
  for (int i = threadIdx.x; i < NBUCKET; i += 256)
    lcur[i] = basemat[c * NBUCKET + i];
  __syncthreads();
  int e0 = c * CHUNK, e1 = min(e0 + CHUNK, N_EDGES);
  for (int e = e0 + threadIdx.x; e < e1; e += 256) {
    int dst = colp[e], src = rowp[e];
    int pos = atomicAdd(&lcur[dst >> BSHIFT], 1);
    packed[pos] = make_int2(src, dst);
  }
}

// ------ C: per-bucket count + scan + sort: writes off, dis, ssrc ------

__global__ __launch_bounds__(256) void k_sortfinal(const int2* __restrict__ packed,
                                                   const int* __restrict__ bbase,
                                                   int* __restrict__ off,
                                                   float* __restrict__ dis,
                                                   int* __restrict__ ssrc) {
  __shared__ int cnt512[512];
  __shared__ int off512[512];
  __shared__ int cur512[512];
  __shared__ int s[256];
  int b = blockIdx.x, t = threadIdx.x;
  int node0 = b << BSHIFT;
  int nn = min(512, N_NODES - node0);
  for (int i = t; i < 512; i += 256) { cnt512[i] = 0; cur512[i] = 0; }
  __syncthreads();
  int r0 = bbase[b], r1 = bbase[b + 1];
  for (int r = r0 + t; r < r1; r += 256)
    atomicAdd(&cnt512[packed[r].y - node0], 1);
  __syncthreads();
  int c0 = cnt512[2 * t], c1 = cnt512[2 * t + 1];
  int ps = c0 + c1;
  s[t] = ps;
  __syncthreads();
  for (int d = 1; d < 256; d <<= 1) {
    int y = (t >= d) ? s[t - d] : 0;
    __syncthreads();
    s[t] += y;
    __syncthreads();
  }
  int ex = s[t] - ps;
  off512[2 * t] = ex;
  off512[2 * t + 1] = ex + c0;
  __syncthreads();
  for (int i = t; i < nn; i += 256) {
    off[node0 + i] = r0 + off512[i];
    dis[node0 + i] = rsqrtf((float)cnt512[i] + 1.0f);
  }
  if (b == NBUCKET - 1 && t == 0) off[N_NODES] = N_EDGES;
  for (int r = r0 + t; r < r1; r += 256) {
    int2 sd = packed[r];
    int d0 = sd.y - node0;
    int pos = r0 + off512[d0] + atomicAdd(&cur512[d0], 1);
    ssrc[pos] = sd.x;
  }
}

// ---------------- W pre-pack into MFMA B-fragment order (bf16) ----------------

__global__ void k_packW1(const float* __restrict__ W, ushort* __restrict__ Wp) {
  int t = blockIdx.x * 256 + threadIdx.x;  // < 8*8*64
  if (t >= 8 * 8 * 64) return;
  int l = t & 63, ks = (t >> 6) & 7, nt = t >> 9;
  int k0 = ks * 32 + (l >> 4) * 8;
  int n = nt * 16 + (l & 15);
  ushort* dst = Wp + (size_t)t * 8;
#pragma unroll
  for (int i = 0; i < 8; i++) dst[i] = f2bf(W[(k0 + i) * DHID + n]);
}

__global__ void k_packW2(const float* __restrict__ W, ushort* __restrict__ Wp) {
  int t = blockIdx.x * 256 + threadIdx.x;  // < 4*4*64
  if (t >= 4 * 4 * 64) return;
  int l = t & 63, ks = (t >> 6) & 3, nt = t >> 8;
  int k0 = ks * 32 + (l >> 4) * 8;
  int n = nt * 16 + (l & 15);
  ushort* dst = Wp + (size_t)t * 8;
#pragma unroll
  for (int i = 0; i < 8; i++) dst[i] = f2bf(W[(k0 + i) * DOUT + n]);
}

// ---------------- GEMM1 (MFMA bf16): h1[N,128]bf16 = x[N,256]f32 @ W1 ----------------

__global__ __launch_bounds__(256) void k_gemm1(const float* __restrict__ x,
                                               const ushort* __restrict__ Wp,
                                               ushort* __restrict__ h1) {
  __shared__ ushort cs[4][16][DHID];  // 16 KB
  int w = threadIdx.x >> 6, l = threadIdx.x & 63;
  int row0 = blockIdx.x * 64 + w * 16;
  bool valid = (row0 < N_NODES);  // N % 16 == 0
  if (valid) {
    f32x4 acc[8];
#pragma unroll
    for (int i = 0; i < 8; i++) acc[i] = (f32x4)(0.f);
    int arow = row0 + (l & 15);
    const float4* xg = (const float4*)(x + (size_t)arow * DIN) + (l >> 4) * 2;
    const bf16x8* wp = (const bf16x8*)Wp;
#pragma unroll
    for (int ks = 0; ks < 8; ks++) {
      float4 a0 = xg[ks * 8];
      float4 a1 = xg[ks * 8 + 1];
      bf16x8 af;
      af[0] = (short)f2bf(a0.x); af[1] = (short)f2bf(a0.y);
      af[2] = (short)f2bf(a0.z); af[3] = (short)f2bf(a0.w);
      af[4] = (short)f2bf(a1.x); af[5] = (short)f2bf(a1.y);
      af[6] = (short)f2bf(a1.z); af[7] = (short)f2bf(a1.w);
#pragma unroll
      for (int nt = 0; nt < 8; nt++) {
        bf16x8 bf = wp[(nt * 8 + ks) * 64 + l];
        acc[nt] = __builtin_amdgcn_mfma_f32_16x16x32_bf16(af, bf, acc[nt], 0, 0, 0);
      }
    }
#pragma unroll
    for (int nt = 0; nt < 8; nt++)
#pragma unroll
      for (int r = 0; r < 4; r++)
        cs[w][(l >> 4) * 4 + r][nt * 16 + (l & 15)] = f2bf(acc[nt][r]);
  }
  __syncthreads();
  if (valid) {
    const uint4* s4 = (const uint4*)&cs[w][l >> 2][(l & 3) * 32];
    uint4* dst = (uint4*)(h1 + (size_t)(row0 + (l >> 2)) * DHID + (l & 3) * 32);
    dst[0] = s4[0]; dst[1] = s4[1]; dst[2] = s4[2]; dst[3] = s4[3];
  }
}

// ---------------- GEMM2 (MFMA bf16): h2[N,64]bf16 = a1[N,128]bf16 @ W2 ----------------

__global__ __launch_bounds__(256) void k_gemm2(const ushort* __restrict__ a1,
                                               const ushort* __restrict__ Wp,
                                               ushort* __restrict__ h2) {
  __shared__ ushort cs[4][16][DOUT];  // 8 KB
  int w = threadIdx.x >> 6, l = threadIdx.x & 63;
  int row0 = blockIdx.x * 64 + w * 16;
  bool valid = (row0 < N_NODES);
  if (valid) {
    f32x4 acc[4];
#pragma unroll
    for (int i = 0; i < 4; i++) acc[i] = (f32x4)(0.f);
    int arow = row0 + (l & 15);
    const bf16x8* ag = (const bf16x8*)(a1 + (size_t)arow * DHID) + (l >> 4);
    const bf16x8* wp = (const bf16x8*)Wp;
#pragma unroll
    for (int ks = 0; ks < 4; ks++) {
      bf16x8 af = ag[ks * 4];
#pragma unroll
      for (int nt = 0; nt < 4; nt++) {
        bf16x8 bf = wp[(nt * 4 + ks) * 64 + l];
        acc[nt] = __builtin_amdgcn_mfma_f32_16x16x32_bf16(af, bf, acc[nt], 0, 0, 0);
      }
    }
#pragma unroll
    for (int nt = 0; nt < 4; nt++)
#pragma unroll
      for (int r = 0; r < 4; r++)
        cs[w][(l >> 4) * 4 + r][nt * 16 + (l & 15)] = f2bf(acc[nt][r]);
  }
  __syncthreads();
  if (valid) {
    const uint4* s4 = (const uint4*)&cs[w][l >> 2][(l & 3) * 16];
    uint4* dst = (uint4*)(h2 + (size_t)(row0 + (l >> 2)) * DOUT + (l & 3) * 16);
    dst[0] = s4[0]; dst[1] = s4[1];
  }
}

// ------- aggregation layer 1 (wave/node): w = dis[src]*dis[dst] on the fly -------

__global__ __launch_bounds__(256) void k_agg1(const uint* __restrict__ h1,
                                              const int* __restrict__ off,
                                              const int* __restrict__ src,
                                              const float* __restrict__ dis,
                                              const float* __restrict__ b1,
                                              uint* __restrict__ a1) {
  int wid  = (blockIdx.x * 256 + threadIdx.x) >> 6;
  int lane = threadIdx.x & 63;
  if (wid >= N_NODES) return;
  float d = dis[wid];
  float d2 = d * d;
  uint hv = h1[(size_t)wid * 64 + lane];
  float ax = __uint_as_float(hv << 16) * d2;
  float ay = __uint_as_float(hv & 0xffff0000u) * d2;
  int o0 = __builtin_amdgcn_readfirstlane(off[wid]);
  int o1 = __builtin_amdgcn_readfirstlane(off[wid + 1]);
  int e = o0;
  for (; e + 4 <= o1; e += 4) {
    int s0 = src[e], s1 = src[e + 1], s2 = src[e + 2], s3 = src[e + 3];
    float w0 = dis[s0] * d, w1 = dis[s1] * d, w2 = dis[s2] * d, w3 = dis[s3] * d;
    uint v0 = h1[(size_t)s0 * 64 + lane];
    uint v1 = h1[(size_t)s1 * 64 + lane];
    uint v2 = h1[(size_t)s2 * 64 + lane];
    uint v3 = h1[(size_t)s3 * 64 + lane];
    ax = fmaf(__uint_as_float(v0 << 16), w0, ax);
    ay = fmaf(__uint_as_float(v0 & 0xffff0000u), w0, ay);
    ax = fmaf(__uint_as_float(v1 << 16), w1, ax);
    ay = fmaf(__uint_as_float(v1 & 0xffff0000u), w1, ay);
    ax = fmaf(__uint_as_float(v2 << 16), w2, ax);
    ay = fmaf(__uint_as_float(v2 & 0xffff0000u), w2, ay);
    ax = fmaf(__uint_as_float(v3 << 16), w3, ax);
    ay = fmaf(__uint_as_float(v3 & 0xffff0000u), w3, ay);
  }
  for (; e < o1; e++) {
    int s = src[e];
    float w0 = dis[s] * d;
    uint v0 = h1[(size_t)s * 64 + lane];
    ax = fmaf(__uint_as_float(v0 << 16), w0, ax);
    ay = fmaf(__uint_as_float(v0 & 0xffff0000u), w0, ay);
  }
  float2 bb = ((const float2*)b1)[lane];
  float rx = fmaxf(ax + bb.x, 0.f);
  float ry = fmaxf(ay + bb.y, 0.f);
  a1[(size_t)wid * 64 + lane] = (uint)f2bf(rx) | ((uint)f2bf(ry) << 16);
}

// -------- aggregation layer 2 + bias + log_softmax -> f32 out --------

__global__ __launch_bounds__(256) void k_agg2(const ushort* __restrict__ h2,
                                              const int* __restrict__ off,
                                              const int* __restrict__ src,
                                              const float* __restrict__ dis,
                                              const float* __restrict__ b2,
                                              float* __restrict__ out) {
  int wid  = (blockIdx.x * 256 + threadIdx.x) >> 6;
  int lane = threadIdx.x & 63;
  if (wid >= N_NODES) return;
  float d = dis[wid];
  float acc = bf2f(h2[(size_t)wid * 64 + lane]) * d * d;
  int o0 = __builtin_amdgcn_readfirstlane(off[wid]);
  int o1 = __builtin_amdgcn_readfirstlane(off[wid + 1]);
  int e = o0;
  for (; e + 4 <= o1; e += 4) {
    int s0 = src[e], s1 = src[e + 1], s2 = src[e + 2], s3 = src[e + 3];
    float w0 = dis[s0] * d, w1 = dis[s1] * d, w2 = dis[s2] * d, w3 = dis[s3] * d;
    float v0 = bf2f(h2[(size_t)s0 * 64 + lane]);
    float v1 = bf2f(h2[(size_t)s1 * 64 + lane]);
    float v2 = bf2f(h2[(size_t)s2 * 64 + lane]);
    float v3 = bf2f(h2[(size_t)s3 * 64 + lane]);
    acc = fmaf(v0, w0, acc);
    acc = fmaf(v1, w1, acc);
    acc = fmaf(v2, w2, acc);
    acc = fmaf(v3, w3, acc);
  }
  for (; e < o1; e++) {
    acc = fmaf(bf2f(h2[(size_t)src[e] * 64 + lane]), dis[src[e]] * d, acc);
  }
  float v = acc + b2[lane];
  float m = v;
#pragma unroll
  for (int sft = 32; sft >= 1; sft >>= 1) m = fmaxf(m, __shfl_xor(m, sft, 64));
  float ex = expf(v - m);
  float sum = ex;
#pragma unroll
  for (int sft = 32; sft >= 1; sft >>= 1) sum += __shfl_xor(sum, sft, 64);
  out[(size_t)wid * 64 + lane] = v - m - logf(sum);
}

// ---------------- launch ----------------

extern "C" void kernel_launch(void* const* d_in, const int* in_sizes, int n_in,
                              void* d_out, int out_size, void* d_ws, size_t ws_size,
                              hipStream_t stream) {
  const float* x  = (const float*)d_in[0];
  const int*   ei = (const int*)d_in[1];
  const float* W1 = (const float*)d_in[2];
  const float* b1 = (const float*)d_in[3];
  const float* W2 = (const float*)d_in[4];
  const float* b2 = (const float*)d_in[5];
  float* out = (float*)d_out;
  const int* rowp = ei;            // sources
  const int* colp = ei + N_EDGES;  // destinations

  char* p = (char*)d_ws;
  size_t o = 0;
  auto alloc = [&](size_t bytes) -> void* {
    void* r = p + o;
    o = (o + bytes + 255) & ~(size_t)255;
    return r;
  };
  int*    off    = (int*)alloc((size_t)(N_NODES + 1) * 4);
  float*  dis    = (float*)alloc((size_t)N_NODES * 4);
  int*    cntmat = (int*)alloc((size_t)NCHUNK * NBUCKET * 4);
  int*    basemat= (int*)alloc((size_t)NCHUNK * NBUCKET * 4);
  int*    btot   = (int*)alloc((size_t)NBUCKET * 4);
  int*    bbase  = (int*)alloc((size_t)(NBUCKET + 1) * 4);
  int2*   packed = (int2*)alloc((size_t)N_EDGES * 8);
  int*    ssrc   = (int*)alloc((size_t)N_EDGES * 4);
  ushort* Wp1    = (ushort*)alloc((size_t)8 * 8 * 64 * 8 * 2);
  ushort* Wp2    = (ushort*)alloc((size_t)4 * 4 * 64 * 8 * 2);
  ushort* h1     = (ushort*)alloc((size_t)N_NODES * DHID * 2);
  ushort* a1     = (ushort*)alloc((size_t)N_NODES * DHID * 2);
  ushort* h2     = h1;  // h1 dead after k_agg1

  k_hist<<<NCHUNK, 256, 0, stream>>>(colp, cntmat);
  k_buckettot<<<NBUCKET, 256, 0, stream>>>(cntmat, btot);
  k_bucketscan<<<1, 256, 0, stream>>>(btot, bbase);
  k_chunkpfx<<<(NBUCKET + 3) / 4, 256, 0, stream>>>(cntmat, bbase, basemat);
  k_binscatter<<<NCHUNK, 256, 0, stream>>>(rowp, colp, basemat, packed);
  k_sortfinal<<<NBUCKET, 256, 0, stream>>>(packed, bbase, off, dis, ssrc);
  k_packW1<<<16, 256, 0, stream>>>(W1, Wp1);
  k_packW2<<<4, 256, 0, stream>>>(W2, Wp2);
  k_gemm1<<<(N_NODES + 63) / 64, 256, 0, stream>>>(x, Wp1, h1);
  k_agg1<<<(N_NODES + 3) / 4, 256, 0, stream>>>((const uint*)h1, off, ssrc, dis, b1, (uint*)a1);
  k_gemm2<<<(N_NODES + 63) / 64, 256, 0, stream>>>(a1, Wp2, h2);
  k_agg2<<<(N_NODES + 3) / 4, 256, 0, stream>>>(h2, off, ssrc, dis, b2, out);
}

// Round 6
// 218.591 us; speedup vs baseline: 2.9530x; 1.0612x over previous
//
#include <hip/hip_runtime.h>

#define N_NODES 100000
#define N_EDGES 1600000
#define DIN 256
#define DHID 128
#define DOUT 64

#define BSHIFT 9
#define NBUCKET 196                 // ceil(100000 / 512)
#define CHUNK 4096
#define NCHUNK ((N_EDGES + CHUNK - 1) / CHUNK)  // 391

typedef __attribute__((ext_vector_type(8))) short bf16x8;
typedef __attribute__((ext_vector_type(4))) float f32x4;

static __device__ __forceinline__ ushort f2bf(float f) {
  union { float f; uint u; } a; a.f = f;
  uint u = a.u;
  uint r = u + 0x7fffu + ((u >> 16) & 1u);  // RNE
  return (ushort)(r >> 16);
}
static __device__ __forceinline__ float bf2f(ushort h) {
  return __uint_as_float(((uint)h) << 16);
}

// ------------- B1: per-chunk bucket histogram (LDS atomics only) -------------

__global__ __launch_bounds__(256) void k_hist(const int* __restrict__ colp,
                                              int* __restrict__ cntmat) {
  __shared__ int h[NBUCKET];
  int c = blockIdx.x;
  for (int i = threadIdx.x; i < NBUCKET; i += 256) h[i] = 0;
  __syncthreads();
  int e0 = c * CHUNK, e1 = min(e0 + CHUNK, N_EDGES);
  for (int e = e0 + threadIdx.x; e < e1; e += 256)
    atomicAdd(&h[colp[e] >> BSHIFT], 1);
  __syncthreads();
  for (int i = threadIdx.x; i < NBUCKET; i += 256)
    cntmat[c * NBUCKET + i] = h[i];
}

// ------------- bucket totals (one block per bucket) -------------

__global__ __launch_bounds__(256) void k_buckettot(const int* __restrict__ cntmat,
                                                   int* __restrict__ btot) {
  __shared__ int s[256];
  int b = blockIdx.x, t = threadIdx.x;
  int sum = 0;
  for (int c = t; c < NCHUNK; c += 256) sum += cntmat[c * NBUCKET + b];
  s[t] = sum;
  __syncthreads();
  for (int d = 128; d > 0; d >>= 1) {
    if (t < d) s[t] += s[t + d];
    __syncthreads();
  }
  if (t == 0) btot[b] = s[0];
}

// ------------- exclusive scan over 196 bucket totals -------------

__global__ void k_bucketscan(const int* __restrict__ btot, int* __restrict__ bbase) {
  __shared__ int s[256];
  int t = threadIdx.x;
  int v = (t < NBUCKET) ? btot[t] : 0;
  s[t] = v;
  __syncthreads();
  for (int d = 1; d < 256; d <<= 1) {
    int y = (t >= d) ? s[t - d] : 0;
    __syncthreads();
    s[t] += y;
    __syncthreads();
  }
  if (t < NBUCKET) bbase[t] = s[t] - v;
  if (t == 0) bbase[NBUCKET] = N_EDGES;
}

// ------------- per-(chunk,bucket) bases: wave-per-bucket prefix over chunks -------------

__global__ __launch_bounds__(256) void k_chunkpfx(const int* __restrict__ cntmat,
                                                  const int* __restrict__ bbase,
                                                  int* __restrict__ basemat) {
  int wid = blockIdx.x * 4 + (threadIdx.x >> 6);
  int lane = threadIdx.x & 63;
  if (wid >= NBUCKET) return;
  int carry = bbase[wid];
  const int NT = (NCHUNK + 63) / 64;
  for (int tt = 0; tt < NT; tt++) {
    int c = tt * 64 + lane;
    int v = (c < NCHUNK) ? cntmat[c * NBUCKET + wid] : 0;
    int incl = v;
#pragma unroll
    for (int d = 1; d < 64; d <<= 1) {
      int y = __shfl_up(incl, d, 64);
      if (lane >= d) incl += y;
    }
    if (c < NCHUNK) basemat[c * NBUCKET + wid] = carry + incl - v;
    carry += __shfl(incl, 63, 64);
  }
}

// ------------- B3: bin edges, 26-bit packed (src | localdst<<17) -------------

__global__ __launch_bounds__(256) void k_binscatter(const int* __restrict__ rowp,
                                                    const int* __restrict__ colp,
                                                    const int* __restrict__ basemat,
                                                    uint* __restrict__ packed) {
  __shared__ int lcur[NBUCKET];
  int c = blockIdx.x;
  for (int i = threadIdx.x; i < NBUCKET; i += 256)
    lcur[i] = basemat[c * NBUCKET + i];
  __syncthreads();
  int e0 = c * CHUNK, e1 = min(e0 + CHUNK, N_EDGES);
  for (int e = e0 + threadIdx.x; e < e1; e += 256) {
    int dst = colp[e], src = rowp[e];
    int pos = atomicAdd(&lcur[dst >> BSHIFT], 1);
    packed[pos] = (uint)src | ((uint)(dst & 511) << 17);
  }
}

// ------ C: per-bucket count + scan + sort: writes off, dis, ssrc ------

__global__ __launch_bounds__(256) void k_sortfinal(const uint* __restrict__ packed,
                                                   const int* __restrict__ bbase,
                                                   int* __restrict__ off,
                                                   float* __restrict__ dis,
                                                   int* __restrict__ ssrc) {
  __shared__ int cnt512[512];
  __shared__ int off512[512];
  __shared__ int cur512[512];
  __shared__ int s[256];
  int b = blockIdx.x, t = threadIdx.x;
  int node0 = b << BSHIFT;
  int nn = min(512, N_NODES - node0);
  for (int i = t; i < 512; i += 256) { cnt512[i] = 0; cur512[i] = 0; }
  __syncthreads();
  int r0 = bbase[b], r1 = bbase[b + 1];
  for (int r = r0 + t; r < r1; r += 256)
    atomicAdd(&cnt512[packed[r] >> 17], 1);
  __syncthreads();
  int c0 = cnt512[2 * t], c1 = cnt512[2 * t + 1];
  int ps = c0 + c1;
  s[t] = ps;
  __syncthreads();
  for (int d = 1; d < 256; d <<= 1) {
    int y = (t >= d) ? s[t - d] : 0;
    __syncthreads();
    s[t] += y;
    __syncthreads();
  }
  int ex = s[t] - ps;
  off512[2 * t] = ex;
  off512[2 * t + 1] = ex + c0;
  __syncthreads();
  for (int i = t; i < nn; i += 256) {
    off[node0 + i] = r0 + off512[i];
    dis[node0 + i] = rsqrtf((float)cnt512[i] + 1.0f);
  }
  if (b == NBUCKET - 1 && t == 0) off[N_NODES] = N_EDGES;
  for (int r = r0 + t; r < r1; r += 256) {
    uint sd = packed[r];
    int d0 = sd >> 17;
    int pos = r0 + off512[d0] + atomicAdd(&cur512[d0], 1);
    ssrc[pos] = (int)(sd & 0x1FFFFu);
  }
}

// ---------------- W pre-pack into MFMA B-fragment order (bf16) ----------------

__global__ void k_packW1(const float* __restrict__ W, ushort* __restrict__ Wp) {
  int t = blockIdx.x * 256 + threadIdx.x;  // < 8*8*64
  if (t >= 8 * 8 * 64) return;
  int l = t & 63, ks = (t >> 6) & 7, nt = t >> 9;
  int k0 = ks * 32 + (l >> 4) * 8;
  int n = nt * 16 + (l & 15);
  ushort* dst = Wp + (size_t)t * 8;
#pragma unroll
  for (int i = 0; i < 8; i++) dst[i] = f2bf(W[(k0 + i) * DHID + n]);
}

__global__ void k_packW2(const float* __restrict__ W, ushort* __restrict__ Wp) {
  int t = blockIdx.x * 256 + threadIdx.x;  // < 4*4*64
  if (t >= 4 * 4 * 64) return;
  int l = t & 63, ks = (t >> 6) & 3, nt = t >> 8;
  int k0 = ks * 32 + (l >> 4) * 8;
  int n = nt * 16 + (l & 15);
  ushort* dst = Wp + (size_t)t * 8;
#pragma unroll
  for (int i = 0; i < 8; i++) dst[i] = f2bf(W[(k0 + i) * DOUT + n]);
}

// ---------------- GEMM1 (MFMA bf16): h1[N,128]bf16 = x[N,256]f32 @ W1 ----------------

__global__ __launch_bounds__(256) void k_gemm1(const float* __restrict__ x,
                                               const ushort* __restrict__ Wp,
                                               ushort* __restrict__ h1) {
  __shared__ ushort cs[4][16][DHID];  // 16 KB
  int w = threadIdx.x >> 6, l = threadIdx.x & 63;
  int row0 = blockIdx.x * 64 + w * 16;
  bool valid = (row0 < N_NODES);  // N % 16 == 0
  if (valid) {
    f32x4 acc[8];
#pragma unroll
    for (int i = 0; i < 8; i++) acc[i] = (f32x4)(0.f);
    int arow = row0 + (l & 15);
    const float4* xg = (const float4*)(x + (size_t)arow * DIN) + (l >> 4) * 2;
    const bf16x8* wp = (const bf16x8*)Wp;
    // hoist all A loads for max memory-level parallelism
    float4 a[16];
#pragma unroll
    for (int ks = 0; ks < 8; ks++) {
      a[2 * ks]     = xg[ks * 8];
      a[2 * ks + 1] = xg[ks * 8 + 1];
    }
#pragma unroll
    for (int ks = 0; ks < 8; ks++) {
      float4 a0 = a[2 * ks];
      float4 a1 = a[2 * ks + 1];
      bf16x8 af;
      af[0] = (short)f2bf(a0.x); af[1] = (short)f2bf(a0.y);
      af[2] = (short)f2bf(a0.z); af[3] = (short)f2bf(a0.w);
      af[4] = (short)f2bf(a1.x); af[5] = (short)f2bf(a1.y);
      af[6] = (short)f2bf(a1.z); af[7] = (short)f2bf(a1.w);
#pragma unroll
      for (int nt = 0; nt < 8; nt++) {
        bf16x8 bf = wp[(nt * 8 + ks) * 64 + l];
        acc[nt] = __builtin_amdgcn_mfma_f32_16x16x32_bf16(af, bf, acc[nt], 0, 0, 0);
      }
    }
#pragma unroll
    for (int nt = 0; nt < 8; nt++)
#pragma unroll
      for (int r = 0; r < 4; r++)
        cs[w][(l >> 4) * 4 + r][nt * 16 + (l & 15)] = f2bf(acc[nt][r]);
  }
  __syncthreads();
  if (valid) {
    const uint4* s4 = (const uint4*)&cs[w][l >> 2][(l & 3) * 32];
    uint4* dst = (uint4*)(h1 + (size_t)(row0 + (l >> 2)) * DHID + (l & 3) * 32);
    dst[0] = s4[0]; dst[1] = s4[1]; dst[2] = s4[2]; dst[3] = s4[3];
  }
}

// ------- FUSED agg1 + GEMM2: block = 16 nodes / 4 waves -------
// Wave w gathers 4 nodes' a-rows (bias+ReLU, bf16 -> LDS), then computes
// n-tile w of a1[16,128] @ W2[128,64] via MFMA and writes h2 directly.

__global__ __launch_bounds__(256) void k_agg1g2(const uint* __restrict__ h1,
                                                const int* __restrict__ off,
                                                const int* __restrict__ src,
                                                const float* __restrict__ dis,
                                                const float* __restrict__ b1,
                                                const ushort* __restrict__ Wp2,
                                                ushort* __restrict__ h2) {
  __shared__ ushort as[16][136];  // padded: row stride 272 B
  int w = threadIdx.x >> 6, lane = threadIdx.x & 63;
  int nb0 = blockIdx.x * 16;  // 100000 % 16 == 0
  float2 bb = ((const float2*)b1)[lane];
#pragma unroll
  for (int i = 0; i < 4; i++) {
    int wid = nb0 + w * 4 + i;
    float d = dis[wid];
    float d2 = d * d;
    uint hv = h1[(size_t)wid * 64 + lane];
    float ax = __uint_as_float(hv << 16) * d2;
    float ay = __uint_as_float(hv & 0xffff0000u) * d2;
    int o0 = __builtin_amdgcn_readfirstlane(off[wid]);
    int o1 = __builtin_amdgcn_readfirstlane(off[wid + 1]);
    int e = o0;
    for (; e + 4 <= o1; e += 4) {
      int s0 = src[e], s1 = src[e + 1], s2 = src[e + 2], s3 = src[e + 3];
      float w0 = dis[s0] * d, w1 = dis[s1] * d, w2 = dis[s2] * d, w3 = dis[s3] * d;
      uint v0 = h1[(size_t)s0 * 64 + lane];
      uint v1 = h1[(size_t)s1 * 64 + lane];
      uint v2 = h1[(size_t)s2 * 64 + lane];
      uint v3 = h1[(size_t)s3 * 64 + lane];
      ax = fmaf(__uint_as_float(v0 << 16), w0, ax);
      ay = fmaf(__uint_as_float(v0 & 0xffff0000u), w0, ay);
      ax = fmaf(__uint_as_float(v1 << 16), w1, ax);
      ay = fmaf(__uint_as_float(v1 & 0xffff0000u), w1, ay);
      ax = fmaf(__uint_as_float(v2 << 16), w2, ax);
      ay = fmaf(__uint_as_float(v2 & 0xffff0000u), w2, ay);
      ax = fmaf(__uint_as_float(v3 << 16), w3, ax);
      ay = fmaf(__uint_as_float(v3 & 0xffff0000u), w3, ay);
    }
    for (; e < o1; e++) {
      int s = src[e];
      float w0 = dis[s] * d;
      uint v0 = h1[(size_t)s * 64 + lane];
      ax = fmaf(__uint_as_float(v0 << 16), w0, ax);
      ay = fmaf(__uint_as_float(v0 & 0xffff0000u), w0, ay);
    }
    float rx = fmaxf(ax + bb.x, 0.f);
    float ry = fmaxf(ay + bb.y, 0.f);
    ((uint*)&as[w * 4 + i][0])[lane] = (uint)f2bf(rx) | ((uint)f2bf(ry) << 16);
  }
  __syncthreads();
  // GEMM2 epilogue: wave w computes cols w*16 .. w*16+15
  f32x4 acc = (f32x4)(0.f);
  const bf16x8* wp = (const bf16x8*)Wp2;
#pragma unroll
  for (int ks = 0; ks < 4; ks++) {
    bf16x8 af = *(const bf16x8*)&as[lane & 15][ks * 32 + (lane >> 4) * 8];
    bf16x8 bf = wp[(w * 4 + ks) * 64 + lane];
    acc = __builtin_amdgcn_mfma_f32_16x16x32_bf16(af, bf, acc, 0, 0, 0);
  }
#pragma unroll
  for (int r = 0; r < 4; r++) {
    int row = (lane >> 4) * 4 + r;
    h2[(size_t)(nb0 + row) * DOUT + w * 16 + (lane & 15)] = f2bf(acc[r]);
  }
}

// -------- aggregation layer 2 + bias + log_softmax -> f32 out --------

__global__ __launch_bounds__(256) void k_agg2(const ushort* __restrict__ h2,
                                              const int* __restrict__ off,
                                              const int* __restrict__ src,
                                              const float* __restrict__ dis,
                                              const float* __restrict__ b2,
                                              float* __restrict__ out) {
  int wid  = (blockIdx.x * 256 + threadIdx.x) >> 6;
  int lane = threadIdx.x & 63;
  if (wid >= N_NODES) return;
  float d = dis[wid];
  float acc = bf2f(h2[(size_t)wid * 64 + lane]) * d * d;
  int o0 = __builtin_amdgcn_readfirstlane(off[wid]);
  int o1 = __builtin_amdgcn_readfirstlane(off[wid + 1]);
  int e = o0;
  for (; e + 4 <= o1; e += 4) {
    int s0 = src[e], s1 = src[e + 1], s2 = src[e + 2], s3 = src[e + 3];
    float w0 = dis[s0] * d, w1 = dis[s1] * d, w2 = dis[s2] * d, w3 = dis[s3] * d;
    float v0 = bf2f(h2[(size_t)s0 * 64 + lane]);
    float v1 = bf2f(h2[(size_t)s1 * 64 + lane]);
    float v2 = bf2f(h2[(size_t)s2 * 64 + lane]);
    float v3 = bf2f(h2[(size_t)s3 * 64 + lane]);
    acc = fmaf(v0, w0, acc);
    acc = fmaf(v1, w1, acc);
    acc = fmaf(v2, w2, acc);
    acc = fmaf(v3, w3, acc);
  }
  for (; e < o1; e++) {
    acc = fmaf(bf2f(h2[(size_t)src[e] * 64 + lane]), dis[src[e]] * d, acc);
  }
  float v = acc + b2[lane];
  float m = v;
#pragma unroll
  for (int sft = 32; sft >= 1; sft >>= 1) m = fmaxf(m, __shfl_xor(m, sft, 64));
  float ex = expf(v - m);
  float sum = ex;
#pragma unroll
  for (int sft = 32; sft >= 1; sft >>= 1) sum += __shfl_xor(sum, sft, 64);
  out[(size_t)wid * 64 + lane] = v - m - logf(sum);
}

// ---------------- launch ----------------

extern "C" void kernel_launch(void* const* d_in, const int* in_sizes, int n_in,
                              void* d_out, int out_size, void* d_ws, size_t ws_size,
                              hipStream_t stream) {
  const float* x  = (const float*)d_in[0];
  const int*   ei = (const int*)d_in[1];
  const float* W1 = (const float*)d_in[2];
  const float* b1 = (const float*)d_in[3];
  const float* W2 = (const float*)d_in[4];
  const float* b2 = (const float*)d_in[5];
  float* out = (float*)d_out;
  const int* rowp = ei;            // sources
  const int* colp = ei + N_EDGES;  // destinations

  char* p = (char*)d_ws;
  size_t o = 0;
  auto alloc = [&](size_t bytes) -> void* {
    void* r = p + o;
    o = (o + bytes + 255) & ~(size_t)255;
    return r;
  };
  int*    off    = (int*)alloc((size_t)(N_NODES + 1) * 4);
  float*  dis    = (float*)alloc((size_t)N_NODES * 4);
  int*    cntmat = (int*)alloc((size_t)NCHUNK * NBUCKET * 4);
  int*    basemat= (int*)alloc((size_t)NCHUNK * NBUCKET * 4);
  int*    btot   = (int*)alloc((size_t)NBUCKET * 4);
  int*    bbase  = (int*)alloc((size_t)(NBUCKET + 1) * 4);
  uint*   packed = (uint*)alloc((size_t)N_EDGES * 4);
  int*    ssrc   = (int*)alloc((size_t)N_EDGES * 4);
  ushort* Wp1    = (ushort*)alloc((size_t)8 * 8 * 64 * 8 * 2);
  ushort* Wp2    = (ushort*)alloc((size_t)4 * 4 * 64 * 8 * 2);
  ushort* h1     = (ushort*)alloc((size_t)N_NODES * DHID * 2);   // 25.6 MB
  ushort* h2     = (ushort*)alloc((size_t)N_NODES * DOUT * 2);   // 12.8 MB

  k_hist<<<NCHUNK, 256, 0, stream>>>(colp, cntmat);
  k_buckettot<<<NBUCKET, 256, 0, stream>>>(cntmat, btot);
  k_bucketscan<<<1, 256, 0, stream>>>(btot, bbase);
  k_chunkpfx<<<(NBUCKET + 3) / 4, 256, 0, stream>>>(cntmat, bbase, basemat);
  k_binscatter<<<NCHUNK, 256, 0, stream>>>(rowp, colp, basemat, packed);
  k_sortfinal<<<NBUCKET, 256, 0, stream>>>(packed, bbase, off, dis, ssrc);
  k_packW1<<<16, 256, 0, stream>>>(W1, Wp1);
  k_packW2<<<4, 256, 0, stream>>>(W2, Wp2);
  k_gemm1<<<(N_NODES + 63) / 64, 256, 0, stream>>>(x, Wp1, h1);
  k_agg1g2<<<N_NODES / 16, 256, 0, stream>>>((const uint*)h1, off, ssrc, dis, b1, Wp2, h2);
  k_agg2<<<(N_NODES + 3) / 4, 256, 0, stream>>>(h2, off, ssrc, dis, b2, out);
}